// Round 4
// baseline (307.424 us; speedup 1.0000x reference)
//
#include <hip/hip_runtime.h>
#include <stdint.h>

// One thread = one 22-float row. No LDS, no barriers: a row is 88 B, so the
// per-lane stride-88 vector loads/stores are merged by L1/MSHR (reads) and
// L2 write-combining (stores, every line fully covered) back into full-line
// HBM traffic. Wave = load -> compute -> store, fully independent.
typedef float fvec2 __attribute__((ext_vector_type(2)));
typedef float fvec4 __attribute__((ext_vector_type(4)));

__device__ __forceinline__ fvec4 ld4(const float* p) {
    fvec4 v; __builtin_memcpy(&v, p, 16); return v;  // 8B-aligned dwordx4
}
__device__ __forceinline__ void st4(float* p, fvec4 v) {
    __builtin_memcpy(p, &v, 16);
}
__device__ __forceinline__ fvec2 ld2(const float* p) {
    fvec2 v; __builtin_memcpy(&v, p, 8); return v;
}
__device__ __forceinline__ void st2(float* p, fvec2 v) {
    __builtin_memcpy(p, &v, 8);
}

__global__ __launch_bounds__(256) void se3_ham_kernel(
    const float* __restrict__ in, float* __restrict__ out, int n_rows) {
    const int row = blockIdx.x * 256 + threadIdx.x;
    if (row >= n_rows) return;

    const float* p = in + (size_t)row * 22;
    const fvec4 a0 = ld4(p +  0);   // x0 x1 x2 R00
    const fvec4 a1 = ld4(p +  4);   // R01 R02 R10 R11
    const fvec4 a2 = ld4(p +  8);   // R12 R20 R21 R22
    const fvec4 a3 = ld4(p + 12);   // qv0 qv1 qv2 qw0
    const fvec4 a4 = ld4(p + 16);   // qw1 qw2 u0 u1
    const fvec2 a5 = ld2(p + 20);   // u2 u3

    const float R00=a0.w, R01=a1.x, R02=a1.y;
    const float R10=a1.z, R11=a1.w, R12=a2.x;
    const float R20=a2.y, R21=a2.z, R22=a2.w;
    const float qv0=a3.x, qv1=a3.y, qv2=a3.z;
    const float qw0=a3.w, qw1=a4.x, qw2=a4.y;
    const float u0 =a4.z, u1 =a4.w, u2 =a5.x, u3=a5.y;

    // constants (double-derived, matching numpy's float32-cast values)
    const float M1d   = (float)(1.0 / (1.0 / 0.027));   // inv(M*I) diag = 0.027
    const float Minv  = (float)(1.0 / 0.027);           // M1_INV diag
    const float Jx    = (float)2.3951e-05;
    const float Jz    = (float)3.2347e-05;
    const float Jxinv = (float)(1.0 / 2.3951e-05);
    const float Jzinv = (float)(1.0 / 3.2347e-05);
    const float MG    = (float)(0.027 * 9.81);

    // momenta
    const float pv0 = M1d * qv0, pv1 = M1d * qv1, pv2 = M1d * qv2;
    const float pw0 = Jx * qw0,  pw1 = Jx * qw1,  pw2 = Jz * qw2;
    // gradients
    const float hv0 = Minv * pv0, hv1 = Minv * pv1, hv2 = Minv * pv2;
    const float hw0 = Jxinv * pw0, hw1 = Jxinv * pw1, hw2 = Jzinv * pw2;

    // dpv = cross(pv, hw) - MG*R_row2 + (0,0,u0)
    const float dpv0 = (pv1*hw2 - pv2*hw1) - MG*R20;
    const float dpv1 = (pv2*hw0 - pv0*hw2) - MG*R21;
    const float dpv2 = (pv0*hw1 - pv1*hw0) - MG*R22 + u0;
    // dpw = cross(pw, hw) + cross(pv, hv) + (u1,u2,u3)
    const float dpw0 = (pw1*hw2 - pw2*hw1) + (pv1*hv2 - pv2*hv1) + u1;
    const float dpw1 = (pw2*hw0 - pw0*hw2) + (pv2*hv0 - pv0*hv2) + u2;
    const float dpw2 = (pw0*hw1 - pw1*hw0) + (pv0*hv1 - pv1*hv0) + u3;

    fvec4 r0, r1, r2, r3, r4;
    fvec2 r5;
    // dx = R * dHdpv
    r0.x = R00*hv0 + R01*hv1 + R02*hv2;
    r0.y = R10*hv0 + R11*hv1 + R12*hv2;
    r0.z = R20*hv0 + R21*hv1 + R22*hv2;
    // dR rows: cross(R_row_i, hw)
    r0.w = R01*hw2 - R02*hw1;
    r1.x = R02*hw0 - R00*hw2;  r1.y = R00*hw1 - R01*hw0;
    r1.z = R11*hw2 - R12*hw1;  r1.w = R12*hw0 - R10*hw2;
    r2.x = R10*hw1 - R11*hw0;
    r2.y = R21*hw2 - R22*hw1;  r2.z = R22*hw0 - R20*hw2;  r2.w = R20*hw1 - R21*hw0;
    // dv = Minv * dpv ; dw = Jinv * dpw
    r3.x = Minv * dpv0;  r3.y = Minv * dpv1;  r3.z = Minv * dpv2;
    r3.w = Jxinv * dpw0;
    r4.x = Jxinv * dpw1; r4.y = Jzinv * dpw2;
    // trailing zeros
    r4.z = 0.0f; r4.w = 0.0f;
    r5.x = 0.0f; r5.y = 0.0f;

    float* q = out + (size_t)row * 22;
    st4(q +  0, r0);
    st4(q +  4, r1);
    st4(q +  8, r2);
    st4(q + 12, r3);
    st4(q + 16, r4);
    st2(q + 20, r5);
}

extern "C" void kernel_launch(void* const* d_in, const int* in_sizes, int n_in,
                              void* d_out, int out_size, void* d_ws, size_t ws_size,
                              hipStream_t stream) {
    // d_in[0] = t (unused scalar), d_in[1] = input [BS, 22] float32
    const float* x = (const float*)d_in[1];
    float* y = (float*)d_out;
    const int n_rows = in_sizes[1] / 22;
    const int blocks = (n_rows + 255) / 256;
    se3_ham_kernel<<<blocks, 256, 0, stream>>>(x, y, n_rows);
}

// Round 6
// 284.592 us; speedup vs baseline: 1.0802x; 1.0802x over previous
//
#include <hip/hip_runtime.h>
#include <stdint.h>

#define RPB 256  // threads per block = rows per block (4 waves x 64 rows)

// Native clang vector type: __builtin_nontemporal_* requires a vector of
// scalar types, not HIP's struct float4. Same layout/alignment (16B).
typedef float fvec4 __attribute__((ext_vector_type(4)));

// Wave-private staging: each 64-lane wave owns 64 rows and a private LDS
// slice (64*22 floats = 5632 B). DS ops within a wave are ordered by the
// compiler's lgkmcnt discipline; no __syncthreads() anywhere, so each wave
// streams fully independently. Full 64-row tiles (the only case that occurs
// for n_rows % 64 == 0) take an unrolled path that issues all 6 global
// loads back-to-back before any ds_write (incremental vmcnt drain), and all
// 6 ds_reads before any global store in the output phase.
__global__ __launch_bounds__(RPB) void se3_ham_kernel(
    const float* __restrict__ in, float* __restrict__ out, int n_rows) {
    __shared__ float s[RPB * 22];

    const int wave = threadIdx.x >> 6;
    const int lane = threadIdx.x & 63;
    const int row0 = blockIdx.x * RPB + (wave << 6);  // this wave's first row
    if (row0 >= n_rows) return;  // safe: no block-level barriers below
    int count = n_rows - row0;
    if (count > 64) count = 64;

    float* const sw = s + wave * (64 * 22);
    fvec4* const s4 = (fvec4*)sw;

    const float* gin  = in + (size_t)row0 * 22;
    const fvec4* gin4 = (const fvec4*)gin;
    const bool full = (count == 64);

    // ---- phase A: coalesced load global -> LDS (nontemporal) ----
    if (full) {
        // 64 rows * 22 floats = 352 float4: 5 full wave-wide iters + half.
        fvec4 v0 = __builtin_nontemporal_load(&gin4[0 * 64 + lane]);
        fvec4 v1 = __builtin_nontemporal_load(&gin4[1 * 64 + lane]);
        fvec4 v2 = __builtin_nontemporal_load(&gin4[2 * 64 + lane]);
        fvec4 v3 = __builtin_nontemporal_load(&gin4[3 * 64 + lane]);
        fvec4 v4 = __builtin_nontemporal_load(&gin4[4 * 64 + lane]);
        fvec4 v5;
        if (lane < 32) v5 = __builtin_nontemporal_load(&gin4[5 * 64 + lane]);
        s4[0 * 64 + lane] = v0;
        s4[1 * 64 + lane] = v1;
        s4[2 * 64 + lane] = v2;
        s4[3 * 64 + lane] = v3;
        s4[4 * 64 + lane] = v4;
        if (lane < 32) s4[5 * 64 + lane] = v5;
    } else {
        const int nf  = count * 22;
        const int nf4 = nf >> 2;
        for (int i = lane; i < nf4; i += 64)
            s4[i] = __builtin_nontemporal_load(&gin4[i]);
        for (int i = (nf4 << 2) + lane; i < nf; i += 64)
            sw[i] = __builtin_nontemporal_load(&gin[i]);
    }
    __builtin_amdgcn_wave_barrier();

    // ---- phase B: per-row physics, in place in this lane's LDS row ----
    if (lane < count) {
        float* p = &sw[lane * 22];
        const float R00=p[3],  R01=p[4],  R02=p[5];
        const float R10=p[6],  R11=p[7],  R12=p[8];
        const float R20=p[9],  R21=p[10], R22=p[11];
        const float qv0=p[12], qv1=p[13], qv2=p[14];
        const float qw0=p[15], qw1=p[16], qw2=p[17];
        const float u0 =p[18], u1 =p[19], u2 =p[20], u3=p[21];

        // constants (double-derived, matching numpy's float32-cast values)
        const float M1d   = (float)(1.0 / (1.0 / 0.027));   // inv(M*I) diag = 0.027
        const float Minv  = (float)(1.0 / 0.027);           // M1_INV diag
        const float Jx    = (float)2.3951e-05;
        const float Jz    = (float)3.2347e-05;
        const float Jxinv = (float)(1.0 / 2.3951e-05);
        const float Jzinv = (float)(1.0 / 3.2347e-05);
        const float MG    = (float)(0.027 * 9.81);

        // momenta
        const float pv0 = M1d * qv0, pv1 = M1d * qv1, pv2 = M1d * qv2;
        const float pw0 = Jx * qw0,  pw1 = Jx * qw1,  pw2 = Jz * qw2;
        // gradients
        const float hv0 = Minv * pv0, hv1 = Minv * pv1, hv2 = Minv * pv2;
        const float hw0 = Jxinv * pw0, hw1 = Jxinv * pw1, hw2 = Jzinv * pw2;

        // dpv = cross(pv, hw) - MG*R_row2 + (0,0,u0)
        const float dpv0 = (pv1*hw2 - pv2*hw1) - MG*R20;
        const float dpv1 = (pv2*hw0 - pv0*hw2) - MG*R21;
        const float dpv2 = (pv0*hw1 - pv1*hw0) - MG*R22 + u0;
        // dpw = cross(pw, hw) + cross(pv, hv) + (u1,u2,u3)
        const float dpw0 = (pw1*hw2 - pw2*hw1) + (pv1*hv2 - pv2*hv1) + u1;
        const float dpw1 = (pw2*hw0 - pw0*hw2) + (pv2*hv0 - pv0*hv2) + u2;
        const float dpw2 = (pw0*hw1 - pw1*hw0) + (pv0*hv1 - pv1*hv0) + u3;

        // dx = R * dHdpv
        p[0] = R00*hv0 + R01*hv1 + R02*hv2;
        p[1] = R10*hv0 + R11*hv1 + R12*hv2;
        p[2] = R20*hv0 + R21*hv1 + R22*hv2;

        // dR rows: cross(R_row_i, hw)
        p[3]  = R01*hw2 - R02*hw1;  p[4]  = R02*hw0 - R00*hw2;  p[5]  = R00*hw1 - R01*hw0;
        p[6]  = R11*hw2 - R12*hw1;  p[7]  = R12*hw0 - R10*hw2;  p[8]  = R10*hw1 - R11*hw0;
        p[9]  = R21*hw2 - R22*hw1;  p[10] = R22*hw0 - R20*hw2;  p[11] = R20*hw1 - R21*hw0;

        // dv = Minv * dpv ; dw = Jinv * dpw
        p[12] = Minv * dpv0;  p[13] = Minv * dpv1;  p[14] = Minv * dpv2;
        p[15] = Jxinv * dpw0; p[16] = Jxinv * dpw1; p[17] = Jzinv * dpw2;

        // trailing zeros
        p[18] = 0.0f; p[19] = 0.0f; p[20] = 0.0f; p[21] = 0.0f;
    }
    __builtin_amdgcn_wave_barrier();

    // ---- phase C: coalesced store LDS -> global (nontemporal) ----
    float* gout  = out + (size_t)row0 * 22;
    fvec4* gout4 = (fvec4*)gout;
    if (full) {
        fvec4 w0 = s4[0 * 64 + lane];
        fvec4 w1 = s4[1 * 64 + lane];
        fvec4 w2 = s4[2 * 64 + lane];
        fvec4 w3 = s4[3 * 64 + lane];
        fvec4 w4 = s4[4 * 64 + lane];
        fvec4 w5;
        if (lane < 32) w5 = s4[5 * 64 + lane];
        __builtin_nontemporal_store(w0, &gout4[0 * 64 + lane]);
        __builtin_nontemporal_store(w1, &gout4[1 * 64 + lane]);
        __builtin_nontemporal_store(w2, &gout4[2 * 64 + lane]);
        __builtin_nontemporal_store(w3, &gout4[3 * 64 + lane]);
        __builtin_nontemporal_store(w4, &gout4[4 * 64 + lane]);
        if (lane < 32) __builtin_nontemporal_store(w5, &gout4[5 * 64 + lane]);
    } else {
        const int nf  = count * 22;
        const int nf4 = nf >> 2;
        for (int i = lane; i < nf4; i += 64)
            __builtin_nontemporal_store(s4[i], &gout4[i]);
        for (int i = (nf4 << 2) + lane; i < nf; i += 64)
            gout[i] = sw[i];
    }
}

extern "C" void kernel_launch(void* const* d_in, const int* in_sizes, int n_in,
                              void* d_out, int out_size, void* d_ws, size_t ws_size,
                              hipStream_t stream) {
    // d_in[0] = t (unused scalar), d_in[1] = input [BS, 22] float32
    const float* x = (const float*)d_in[1];
    float* y = (float*)d_out;
    const int n_rows = in_sizes[1] / 22;
    const int blocks = (n_rows + RPB - 1) / RPB;
    se3_ham_kernel<<<blocks, RPB, 0, stream>>>(x, y, n_rows);
}